// Round 1
// baseline (1481.435 us; speedup 1.0000x reference)
//
#include <hip/hip_runtime.h>
#include <hip/hip_bf16.h>
#include <cstdint>

#define N_HID 384
#define BM 128
#define BN 128
#define BK 64
#define LDK 72   // BK + 8 pad: breaks power-of-2 LDS row stride (2-way max = free)

typedef __attribute__((ext_vector_type(8))) short bf16x8;
typedef __attribute__((ext_vector_type(4))) float f32x4;

static __device__ __forceinline__ short f2bf(float f) {
    union { __hip_bfloat16 h; short s; } u;
    u.h = __float2bfloat16(f);  // RNE
    return u.s;
}

__global__ __launch_bounds__(256) void k_deg(const int* __restrict__ row,
                                             int* __restrict__ deg, int E) {
    int i = blockIdx.x * 256 + threadIdx.x;
    if (i < E) atomicAdd(&deg[row[i]], 1);
}

__global__ __launch_bounds__(256) void k_dis(const int* __restrict__ deg,
                                             float* __restrict__ dis, int N) {
    int i = blockIdx.x * 256 + threadIdx.x;
    if (i < N) dis[i] = rsqrtf((float)deg[i]);
}

// out(bf16)[M][384] = A(f32)[M][384] @ W(f32)[384][384]^T + bias
// 128x128 block tile, BK=64, 4 waves each computing 64x64 via 4x4 of 16x16x32 MFMA.
__global__ __launch_bounds__(256) void k_gemm(const float* __restrict__ A,
                                              const float* __restrict__ W,
                                              const float* __restrict__ bias,
                                              short* __restrict__ out, int M) {
    __shared__ short As[BM][LDK];
    __shared__ short Bs[BN][LDK];
    const int t = threadIdx.x;
    const int n0 = blockIdx.x * BN;          // x fastest: 3 N-blocks share A tile (L2 reuse)
    const int m0 = blockIdx.y * BM;
    const int wave = t >> 6, lane = t & 63;
    const int wm = (wave & 1) * 64, wn = (wave >> 1) * 64;
    const int l16 = lane & 15, quad = lane >> 4;
    const int srow = t >> 4;                 // staging: 16 rows x 16 threads
    const int sk4  = (t & 15) * 4;           // each thread: one float4 per row-slice

    f32x4 acc[4][4] = {};

    for (int kt = 0; kt < N_HID; kt += BK) {
        // stage A tile (fp32 -> bf16), clamp M edge (stores predicated later)
        #pragma unroll
        for (int s = 0; s < 8; s++) {
            int r = srow + s * 16;
            int gm = m0 + r; gm = gm < M ? gm : M - 1;
            const float4 v = *reinterpret_cast<const float4*>(A + (size_t)gm * N_HID + kt + sk4);
            short4 sv = make_short4(f2bf(v.x), f2bf(v.y), f2bf(v.z), f2bf(v.w));
            *reinterpret_cast<short4*>(&As[r][sk4]) = sv;
        }
        // stage B tile = W rows [n0, n0+128) (N=384 divides exactly, no clamp)
        #pragma unroll
        for (int s = 0; s < 8; s++) {
            int r = srow + s * 16;
            const float4 v = *reinterpret_cast<const float4*>(W + (size_t)(n0 + r) * N_HID + kt + sk4);
            short4 sv = make_short4(f2bf(v.x), f2bf(v.y), f2bf(v.z), f2bf(v.w));
            *reinterpret_cast<short4*>(&Bs[r][sk4]) = sv;
        }
        __syncthreads();
        #pragma unroll
        for (int kk = 0; kk < 2; kk++) {
            const int kb = kk * 32 + quad * 8;   // A[m=lane&15][k=quad*8+j]; B mirrors
            bf16x8 af[4], bfr[4];
            #pragma unroll
            for (int i = 0; i < 4; i++)
                af[i] = *reinterpret_cast<const bf16x8*>(&As[wm + i * 16 + l16][kb]);
            #pragma unroll
            for (int j = 0; j < 4; j++)
                bfr[j] = *reinterpret_cast<const bf16x8*>(&Bs[wn + j * 16 + l16][kb]);
            #pragma unroll
            for (int i = 0; i < 4; i++)
                #pragma unroll
                for (int j = 0; j < 4; j++)
                    acc[i][j] = __builtin_amdgcn_mfma_f32_16x16x32_bf16(af[i], bfr[j], acc[i][j], 0, 0, 0);
        }
        __syncthreads();
    }

    // C/D layout: col = lane&15, row = quad*4 + reg  [verified m89/m91]
    #pragma unroll
    for (int j = 0; j < 4; j++) {
        int gn = n0 + wn + j * 16 + l16;
        float bv = bias[gn];
        #pragma unroll
        for (int i = 0; i < 4; i++) {
            int gmb = m0 + wm + i * 16 + quad * 4;
            #pragma unroll
            for (int r = 0; r < 4; r++) {
                int gm = gmb + r;
                if (gm < M) out[(size_t)gm * N_HID + gn] = f2bf(acc[i][j][r] + bv);
            }
        }
    }
}

// one wave per edge: out[col] += dis[row]*dis[col] * h[row]  (384 floats)
__global__ __launch_bounds__(256) void k_scatter(const short* __restrict__ h,
                                                 const int* __restrict__ row,
                                                 const int* __restrict__ col,
                                                 const float* __restrict__ dis,
                                                 float* __restrict__ out, int E) {
    int e = (blockIdx.x * 256 + threadIdx.x) >> 6;
    if (e >= E) return;
    int lane = threadIdx.x & 63;
    int r = row[e], c = col[e];               // wave-uniform -> scalarized
    float norm = dis[r] * dis[c];
    const unsigned int* hr = reinterpret_cast<const unsigned int*>(h + (size_t)r * N_HID);
    float* oc = out + (size_t)c * N_HID;
    #pragma unroll
    for (int s = 0; s < 3; s++) {
        int d = lane + 64 * s;                // dword index 0..191 (2 bf16 each)
        unsigned int p = hr[d];
        float v0 = __uint_as_float(p << 16);
        float v1 = __uint_as_float(p & 0xffff0000u);
        atomicAdd(oc + 2 * d,     v0 * norm);
        atomicAdd(oc + 2 * d + 1, v1 * norm);
    }
}

extern "C" void kernel_launch(void* const* d_in, const int* in_sizes, int n_in,
                              void* d_out, int out_size, void* d_ws, size_t ws_size,
                              hipStream_t stream) {
    const float* x  = (const float*)d_in[0];
    const int*   ei = (const int*)d_in[1];
    const float* W1 = (const float*)d_in[2];
    const float* b1 = (const float*)d_in[3];
    const float* W2 = (const float*)d_in[4];
    const float* b2 = (const float*)d_in[5];
    float* out = (float*)d_out;

    const int N = in_sizes[0] / N_HID;   // 100000
    const int E = in_sizes[1] / 2;       // 200000
    const int* row = ei;
    const int* col = ei + E;

    // ws layout: [deg: N int][dis: N float][h: N*384 bf16]  (~79 MB total)
    char* ws = (char*)d_ws;
    int*   deg = (int*)ws;
    float* dis = (float*)(ws + (1 << 20));
    short* h   = (short*)(ws + (2 << 20));

    hipMemsetAsync(deg, 0, (size_t)N * 4, stream);
    k_deg<<<(E + 255) / 256, 256, 0, stream>>>(row, deg, E);
    k_dis<<<(N + 255) / 256, 256, 0, stream>>>(deg, dis, N);

    dim3 ggrid(N_HID / BN, (N + BM - 1) / BM);   // (3, 782)

    // layer 1: h1 = x@W1^T + b1 ; a1 (=d_out) = scatter(h1)
    k_gemm<<<ggrid, 256, 0, stream>>>(x, W1, b1, h, N);
    hipMemsetAsync(out, 0, (size_t)N * N_HID * sizeof(float), stream);
    k_scatter<<<(size_t)E * 64 / 256 + 1, 256, 0, stream>>>(h, row, col, dis, out, E);

    // layer 2: h2 = a1@W2^T + b2 (reads d_out) ; out = scatter(h2)
    k_gemm<<<ggrid, 256, 0, stream>>>(out, W2, b2, h, N);
    hipMemsetAsync(out, 0, (size_t)N * N_HID * sizeof(float), stream);
    k_scatter<<<(size_t)E * 64 / 256 + 1, 256, 0, stream>>>(h, row, col, dis, out, E);
}

// Round 2
// 635.570 us; speedup vs baseline: 2.3309x; 2.3309x over previous
//
#include <hip/hip_runtime.h>
#include <hip/hip_bf16.h>
#include <cstdint>

#define N_HID 384
#define BM 128
#define BN 128
#define BK 64
#define LDK 72   // BK + 8 pad: breaks power-of-2 LDS row stride

typedef __attribute__((ext_vector_type(8))) short bf16x8;
typedef __attribute__((ext_vector_type(4))) float f32x4;

static __device__ __forceinline__ short f2bf(float f) {
    union { __hip_bfloat16 h; short s; } u;
    u.h = __float2bfloat16(f);  // RNE
    return u.s;
}

__global__ __launch_bounds__(256) void k_deg(const int* __restrict__ row,
                                             int* __restrict__ deg, int E) {
    int i = blockIdx.x * 256 + threadIdx.x;
    if (i < E) atomicAdd(&deg[row[i]], 1);
}

__global__ __launch_bounds__(256) void k_dis(const int* __restrict__ deg,
                                             float* __restrict__ dis, int N) {
    int i = blockIdx.x * 256 + threadIdx.x;
    if (i < N) dis[i] = rsqrtf((float)deg[i]);
}

// ---------- CSR-by-destination build ----------

__global__ __launch_bounds__(256) void k_cnt(const int* __restrict__ col,
                                             int* __restrict__ cnt, int E) {
    int i = blockIdx.x * 256 + threadIdx.x;
    if (i < E) atomicAdd(&cnt[col[i]], 1);
}

// block-level scan: 256 threads x 4 elems = 1024 per block; in-place cnt->offs ok
__global__ __launch_bounds__(256) void k_scan1(const int* __restrict__ cnt,
                                               int* __restrict__ offs,
                                               int* __restrict__ bsum, int N) {
    __shared__ int s[256];
    const int t = threadIdx.x;
    const int base = blockIdx.x * 1024 + t * 4;
    int v[4], tot = 0;
    #pragma unroll
    for (int i = 0; i < 4; i++) { v[i] = (base + i < N) ? cnt[base + i] : 0; tot += v[i]; }
    s[t] = tot;
    __syncthreads();
    #pragma unroll
    for (int off = 1; off < 256; off <<= 1) {
        int x = (t >= off) ? s[t - off] : 0;
        __syncthreads();
        s[t] += x;
        __syncthreads();
    }
    if (t == 255) bsum[blockIdx.x] = s[255];
    int run = s[t] - tot;  // exclusive prefix for this thread
    #pragma unroll
    for (int i = 0; i < 4; i++) { if (base + i < N) offs[base + i] = run; run += v[i]; }
}

__global__ void k_scan2(int* __restrict__ bsum, int nb) {
    if (threadIdx.x == 0 && blockIdx.x == 0) {
        int run = 0;
        for (int i = 0; i < nb; i++) { int v = bsum[i]; bsum[i] = run; run += v; }
    }
}

__global__ __launch_bounds__(256) void k_scan3(int* __restrict__ offs,
                                               const int* __restrict__ bsum, int N) {
    int i = blockIdx.x * 256 + threadIdx.x;
    if (i < N) offs[i] += bsum[i >> 10];
}

// slot fill: src + premultiplied norm per CSR slot
__global__ __launch_bounds__(256) void k_fill(const int* __restrict__ row,
                                              const int* __restrict__ col,
                                              const float* __restrict__ dis,
                                              const int* __restrict__ offs,
                                              int* __restrict__ cur,
                                              int* __restrict__ src,
                                              float* __restrict__ nrm, int E) {
    int e = blockIdx.x * 256 + threadIdx.x;
    if (e >= E) return;
    int r = row[e], c = col[e];
    int slot = offs[c] + atomicAdd(&cur[c], 1);
    src[slot] = r;
    nrm[slot] = dis[r] * dis[c];
}

// ---------- GEMM: out(bf16)[M][384] = A(f32) @ W(f32)^T + bias ----------

__global__ __launch_bounds__(256) void k_gemm(const float* __restrict__ A,
                                              const float* __restrict__ W,
                                              const float* __restrict__ bias,
                                              short* __restrict__ out, int M) {
    __shared__ short As[BM][LDK];
    __shared__ short Bs[BN][LDK];
    const int t = threadIdx.x;
    const int n0 = blockIdx.x * BN;
    const int m0 = blockIdx.y * BM;
    const int wave = t >> 6, lane = t & 63;
    const int wm = (wave & 1) * 64, wn = (wave >> 1) * 64;
    const int l16 = lane & 15, quad = lane >> 4;
    const int srow = t >> 4;
    const int sk4  = (t & 15) * 4;

    f32x4 acc[4][4] = {};

    for (int kt = 0; kt < N_HID; kt += BK) {
        #pragma unroll
        for (int s = 0; s < 8; s++) {
            int r = srow + s * 16;
            int gm = m0 + r; gm = gm < M ? gm : M - 1;
            const float4 v = *reinterpret_cast<const float4*>(A + (size_t)gm * N_HID + kt + sk4);
            short4 sv = make_short4(f2bf(v.x), f2bf(v.y), f2bf(v.z), f2bf(v.w));
            *reinterpret_cast<short4*>(&As[r][sk4]) = sv;
        }
        #pragma unroll
        for (int s = 0; s < 8; s++) {
            int r = srow + s * 16;
            const float4 v = *reinterpret_cast<const float4*>(W + (size_t)(n0 + r) * N_HID + kt + sk4);
            short4 sv = make_short4(f2bf(v.x), f2bf(v.y), f2bf(v.z), f2bf(v.w));
            *reinterpret_cast<short4*>(&Bs[r][sk4]) = sv;
        }
        __syncthreads();
        #pragma unroll
        for (int kk = 0; kk < 2; kk++) {
            const int kb = kk * 32 + quad * 8;
            bf16x8 af[4], bfr[4];
            #pragma unroll
            for (int i = 0; i < 4; i++)
                af[i] = *reinterpret_cast<const bf16x8*>(&As[wm + i * 16 + l16][kb]);
            #pragma unroll
            for (int j = 0; j < 4; j++)
                bfr[j] = *reinterpret_cast<const bf16x8*>(&Bs[wn + j * 16 + l16][kb]);
            #pragma unroll
            for (int i = 0; i < 4; i++)
                #pragma unroll
                for (int j = 0; j < 4; j++)
                    acc[i][j] = __builtin_amdgcn_mfma_f32_16x16x32_bf16(af[i], bfr[j], acc[i][j], 0, 0, 0);
        }
        __syncthreads();
    }

    // C/D layout: col = lane&15, row = quad*4 + reg
    #pragma unroll
    for (int j = 0; j < 4; j++) {
        int gn = n0 + wn + j * 16 + l16;
        float bv = bias[gn];
        #pragma unroll
        for (int i = 0; i < 4; i++) {
            int gmb = m0 + wm + i * 16 + quad * 4;
            #pragma unroll
            for (int r = 0; r < 4; r++) {
                int gm = gmb + r;
                if (gm < M) out[(size_t)gm * N_HID + gn] = f2bf(acc[i][j][r] + bv);
            }
        }
    }
}

// ---------- gather: one wave per destination node, no atomics ----------
// out[c] = sum over incoming slots: nrm[slot] * h[src[slot]]
__global__ __launch_bounds__(256) void k_gather(const short* __restrict__ h,
                                                const int* __restrict__ src,
                                                const float* __restrict__ nrm,
                                                const int* __restrict__ offs,
                                                const int* __restrict__ cur,
                                                float* __restrict__ out, int N) {
    int node = (blockIdx.x * 256 + threadIdx.x) >> 6;
    if (node >= N) return;
    int lane = threadIdx.x & 63;
    int start = offs[node];
    int ecnt  = cur[node];   // in-degree (cursor value after fill)
    float2 acc[3] = {};
    for (int i = 0; i < ecnt; i++) {
        int slot = start + i;
        int s = src[slot];        // wave-uniform -> broadcast
        float w = nrm[slot];
        const unsigned int* hr = reinterpret_cast<const unsigned int*>(h + (size_t)s * N_HID);
        #pragma unroll
        for (int k = 0; k < 3; k++) {
            unsigned int p = hr[lane + 64 * k];
            acc[k].x += w * __uint_as_float(p << 16);
            acc[k].y += w * __uint_as_float(p & 0xffff0000u);
        }
    }
    float2* oc = reinterpret_cast<float2*>(out + (size_t)node * N_HID);
    #pragma unroll
    for (int k = 0; k < 3; k++) oc[lane + 64 * k] = acc[k];
}

extern "C" void kernel_launch(void* const* d_in, const int* in_sizes, int n_in,
                              void* d_out, int out_size, void* d_ws, size_t ws_size,
                              hipStream_t stream) {
    const float* x  = (const float*)d_in[0];
    const int*   ei = (const int*)d_in[1];
    const float* W1 = (const float*)d_in[2];
    const float* b1 = (const float*)d_in[3];
    const float* W2 = (const float*)d_in[4];
    const float* b2 = (const float*)d_in[5];
    float* out = (float*)d_out;

    const int N = in_sizes[0] / N_HID;   // 100000
    const int E = in_sizes[1] / 2;       // 200000
    const int* row = ei;
    const int* col = ei + E;
    const int nb = (N + 1023) / 1024;    // scan blocks

    // ws layout (tight, 256B-aligned chunks)
    auto al = [](size_t x) { return (x + 255) & ~(size_t)255; };
    char* ws = (char*)d_ws;
    size_t o = 0;
    int*   deg  = (int*)(ws + o);  o += al((size_t)N * 4);   // reused as cur after k_dis
    float* dis  = (float*)(ws + o); o += al((size_t)N * 4);
    int*   offs = (int*)(ws + o);  o += al((size_t)N * 4);   // cnt -> offs in place
    int*   bsum = (int*)(ws + o);  o += al((size_t)nb * 4);
    int*   srcA = (int*)(ws + o);  o += al((size_t)E * 4);
    float* nrm  = (float*)(ws + o); o += al((size_t)E * 4);
    short* h    = (short*)(ws + o);                           // N*384 bf16 (76.8 MB)
    int*   cur  = deg;

    // degree (over row) and dis = deg^-0.5
    hipMemsetAsync(deg, 0, (size_t)N * 4, stream);
    k_deg<<<(E + 255) / 256, 256, 0, stream>>>(row, deg, E);
    k_dis<<<(N + 255) / 256, 256, 0, stream>>>(deg, dis, N);

    // CSR by destination
    hipMemsetAsync(offs, 0, (size_t)N * 4, stream);
    k_cnt<<<(E + 255) / 256, 256, 0, stream>>>(col, offs, E);
    k_scan1<<<nb, 256, 0, stream>>>(offs, offs, bsum, N);
    k_scan2<<<1, 64, 0, stream>>>(bsum, nb);
    k_scan3<<<(N + 255) / 256, 256, 0, stream>>>(offs, bsum, N);
    hipMemsetAsync(cur, 0, (size_t)N * 4, stream);   // deg reuse (k_dis done)
    k_fill<<<(E + 255) / 256, 256, 0, stream>>>(row, col, dis, offs, cur, srcA, nrm, E);

    dim3 ggrid(N_HID / BN, (N + BM - 1) / BM);   // (3, 782)
    const int gat_blocks = (int)(((size_t)N * 64 + 255) / 256);

    // layer 1: h1 = x@W1^T + b1 ; a1 (=d_out) = gather(h1)
    k_gemm<<<ggrid, 256, 0, stream>>>(x, W1, b1, h, N);
    k_gather<<<gat_blocks, 256, 0, stream>>>(h, srcA, nrm, offs, cur, out, N);

    // layer 2: h2 = a1@W2^T + b2 ; out = gather(h2)
    k_gemm<<<ggrid, 256, 0, stream>>>(out, W2, b2, h, N);
    k_gather<<<gat_blocks, 256, 0, stream>>>(h, srcA, nrm, offs, cur, out, N);
}

// Round 3
// 595.099 us; speedup vs baseline: 2.4894x; 1.0680x over previous
//
#include <hip/hip_runtime.h>
#include <hip/hip_bf16.h>
#include <cstdint>

#define N_HID 384
#define BM 128
#define BN 128
#define BK 64

typedef __attribute__((ext_vector_type(8))) short bf16x8;
typedef __attribute__((ext_vector_type(4))) float f32x4;

static __device__ __forceinline__ short f2bf(float f) {
    union { __hip_bfloat16 h; short s; } u;
    u.h = __float2bfloat16(f);  // RNE
    return u.s;
}

// async global->LDS, 16B per lane; LDS dest is wave-uniform base + lane*16
static __device__ __forceinline__ void gload_lds16(const void* g, void* l) {
    __builtin_amdgcn_global_load_lds(
        (const __attribute__((address_space(1))) void*)g,
        (__attribute__((address_space(3))) void*)l,
        16, 0, 0);
}

__global__ __launch_bounds__(256) void k_deg(const int* __restrict__ row,
                                             int* __restrict__ deg, int E) {
    int i = blockIdx.x * 256 + threadIdx.x;
    if (i < E) atomicAdd(&deg[row[i]], 1);
}

__global__ __launch_bounds__(256) void k_dis(const int* __restrict__ deg,
                                             float* __restrict__ dis, int N) {
    int i = blockIdx.x * 256 + threadIdx.x;
    if (i < N) dis[i] = rsqrtf((float)deg[i]);
}

// fp32 -> bf16 (RNE), n4 = n/4
__global__ __launch_bounds__(256) void k_cvt(const float* __restrict__ in,
                                             short* __restrict__ out, int n4) {
    int i = blockIdx.x * 256 + threadIdx.x;
    if (i < n4) {
        float4 v = reinterpret_cast<const float4*>(in)[i];
        short4 s = make_short4(f2bf(v.x), f2bf(v.y), f2bf(v.z), f2bf(v.w));
        reinterpret_cast<short4*>(out)[i] = s;
    }
}

// ---------- CSR-by-destination build ----------

__global__ __launch_bounds__(256) void k_cnt(const int* __restrict__ col,
                                             int* __restrict__ cnt, int E) {
    int i = blockIdx.x * 256 + threadIdx.x;
    if (i < E) atomicAdd(&cnt[col[i]], 1);
}

__global__ __launch_bounds__(256) void k_scan1(const int* __restrict__ cnt,
                                               int* __restrict__ offs,
                                               int* __restrict__ bsum, int N) {
    __shared__ int s[256];
    const int t = threadIdx.x;
    const int base = blockIdx.x * 1024 + t * 4;
    int v[4], tot = 0;
    #pragma unroll
    for (int i = 0; i < 4; i++) { v[i] = (base + i < N) ? cnt[base + i] : 0; tot += v[i]; }
    s[t] = tot;
    __syncthreads();
    #pragma unroll
    for (int off = 1; off < 256; off <<= 1) {
        int x = (t >= off) ? s[t - off] : 0;
        __syncthreads();
        s[t] += x;
        __syncthreads();
    }
    if (t == 255) bsum[blockIdx.x] = s[255];
    int run = s[t] - tot;
    #pragma unroll
    for (int i = 0; i < 4; i++) { if (base + i < N) offs[base + i] = run; run += v[i]; }
}

__global__ void k_scan2(int* __restrict__ bsum, int nb) {
    if (threadIdx.x == 0 && blockIdx.x == 0) {
        int run = 0;
        for (int i = 0; i < nb; i++) { int v = bsum[i]; bsum[i] = run; run += v; }
    }
}

__global__ __launch_bounds__(256) void k_scan3(int* __restrict__ offs,
                                               const int* __restrict__ bsum, int N) {
    int i = blockIdx.x * 256 + threadIdx.x;
    if (i < N) offs[i] += bsum[i >> 10];
}

__global__ __launch_bounds__(256) void k_fill(const int* __restrict__ row,
                                              const int* __restrict__ col,
                                              const float* __restrict__ dis,
                                              const int* __restrict__ offs,
                                              int* __restrict__ cur,
                                              int* __restrict__ src,
                                              float* __restrict__ nrm, int E) {
    int e = blockIdx.x * 256 + threadIdx.x;
    if (e >= E) return;
    int r = row[e], c = col[e];
    int slot = offs[c] + atomicAdd(&cur[c], 1);
    src[slot] = r;
    nrm[slot] = dis[r] * dis[c];
}

// ---------- GEMM (m97 structure): out(bf16) = A(bf16) @ W(bf16)^T + bias ----------
// 128x128 tile, BK=64, global_load_lds width-16 staging, unpadded LDS tiles.
__global__ __launch_bounds__(256) void k_gemm(const short* __restrict__ A,
                                              const short* __restrict__ W,
                                              const float* __restrict__ bias,
                                              short* __restrict__ out, int M) {
    __shared__ short As[BM][BK];   // 16 KB, NO pad: global_load_lds needs contiguous lane*16
    __shared__ short Bs[BN][BK];   // 16 KB
    const int t = threadIdx.x;
    const int n0 = blockIdx.x * BN;          // x fastest: 3 n-blocks reuse A via L2
    const int m0 = blockIdx.y * BM;
    const int wave = t >> 6, lane = t & 63;
    const int wm = (wave & 1) * 64, wn = (wave >> 1) * 64;
    const int l16 = lane & 15, quad = lane >> 4;
    const int srow  = wave * 8 + (lane >> 3);  // staging row within 32-row slab
    const int scol8 = (lane & 7) * 8;          // staging col (elements)

    f32x4 acc[4][4] = {};

    for (int kt = 0; kt < N_HID; kt += BK) {
        __syncthreads();   // all waves done reading previous tile
        #pragma unroll
        for (int p = 0; p < 4; p++) {
            int gm = m0 + p * 32 + srow;
            gm = gm < M ? gm : M - 1;
            gload_lds16(A + (size_t)gm * N_HID + kt + scol8, &As[p * 32 + wave * 8][0]);
        }
        #pragma unroll
        for (int p = 0; p < 4; p++) {
            int gn = n0 + p * 32 + srow;
            gload_lds16(W + (size_t)gn * N_HID + kt + scol8, &Bs[p * 32 + wave * 8][0]);
        }
        __syncthreads();   // vmcnt(0) drained before barrier -> tiles ready

        #pragma unroll
        for (int kk = 0; kk < 2; kk++) {
            const int kb = kk * 32 + quad * 8;   // A[m=lane&15][k=quad*8+j]
            bf16x8 af[4], bfr[4];
            #pragma unroll
            for (int i = 0; i < 4; i++)
                af[i] = *reinterpret_cast<const bf16x8*>(&As[wm + i * 16 + l16][kb]);
            #pragma unroll
            for (int j = 0; j < 4; j++)
                bfr[j] = *reinterpret_cast<const bf16x8*>(&Bs[wn + j * 16 + l16][kb]);
            #pragma unroll
            for (int i = 0; i < 4; i++)
                #pragma unroll
                for (int j = 0; j < 4; j++)
                    acc[i][j] = __builtin_amdgcn_mfma_f32_16x16x32_bf16(af[i], bfr[j], acc[i][j], 0, 0, 0);
        }
    }

    // C/D layout: col = lane&15, row = quad*4 + reg
    #pragma unroll
    for (int j = 0; j < 4; j++) {
        int gn = n0 + wn + j * 16 + l16;
        float bv = bias[gn];
        #pragma unroll
        for (int i = 0; i < 4; i++) {
            int gmb = m0 + wm + i * 16 + quad * 4;
            #pragma unroll
            for (int r = 0; r < 4; r++) {
                int gm = gmb + r;
                if (gm < M) out[(size_t)gm * N_HID + gn] = f2bf(acc[i][j][r] + bv);
            }
        }
    }
}

// ---------- gather: one wave per destination node, no atomics ----------
template <bool BF16OUT>
__global__ __launch_bounds__(256) void k_gather(const short* __restrict__ h,
                                                const int* __restrict__ src,
                                                const float* __restrict__ nrm,
                                                const int* __restrict__ offs,
                                                const int* __restrict__ cur,
                                                void* __restrict__ outv, int N) {
    int node = (blockIdx.x * 256 + threadIdx.x) >> 6;
    if (node >= N) return;
    int lane = threadIdx.x & 63;
    int start = offs[node];
    int ecnt  = cur[node];   // in-degree
    float2 acc[3] = {};
    for (int i = 0; i < ecnt; i++) {
        int slot = start + i;
        int s = src[slot];        // wave-uniform -> scalarized
        float w = nrm[slot];
        const unsigned int* hr = reinterpret_cast<const unsigned int*>(h + (size_t)s * N_HID);
        #pragma unroll
        for (int k = 0; k < 3; k++) {
            unsigned int p = hr[lane + 64 * k];
            acc[k].x += w * __uint_as_float(p << 16);
            acc[k].y += w * __uint_as_float(p & 0xffff0000u);
        }
    }
    if (BF16OUT) {
        unsigned int* oc = reinterpret_cast<unsigned int*>(outv) + (size_t)node * 192;
        #pragma unroll
        for (int k = 0; k < 3; k++) {
            unsigned int lo = (unsigned int)(unsigned short)f2bf(acc[k].x);
            unsigned int hi = (unsigned int)(unsigned short)f2bf(acc[k].y);
            oc[lane + 64 * k] = lo | (hi << 16);
        }
    } else {
        float2* oc = reinterpret_cast<float2*>(outv) + (size_t)node * 192;
        #pragma unroll
        for (int k = 0; k < 3; k++) oc[lane + 64 * k] = acc[k];
    }
}

extern "C" void kernel_launch(void* const* d_in, const int* in_sizes, int n_in,
                              void* d_out, int out_size, void* d_ws, size_t ws_size,
                              hipStream_t stream) {
    const float* x  = (const float*)d_in[0];
    const int*   ei = (const int*)d_in[1];
    const float* W1 = (const float*)d_in[2];
    const float* b1 = (const float*)d_in[3];
    const float* W2 = (const float*)d_in[4];
    const float* b2 = (const float*)d_in[5];
    float* out = (float*)d_out;

    const int N = in_sizes[0] / N_HID;   // 100000
    const int E = in_sizes[1] / 2;       // 200000
    const int* row = ei;
    const int* col = ei + E;
    const int nb = (N + 1023) / 1024;

    // d_out doubles as scratch (disjoint lifetimes; gather-2 fully rewrites it):
    //   xb = d_out[0 : N*384 bf16]  (76.8 MB) — live cvt -> gemm1
    //   a1 = d_out[N*384 : 2*N*384 bf16]      — live gather1 -> gemm2
    short* xb = (short*)d_out;
    short* a1 = (short*)d_out + (size_t)N * N_HID;

    // ws layout
    auto al = [](size_t v) { return (v + 255) & ~(size_t)255; };
    char* ws = (char*)d_ws;
    size_t o = 0;
    int*   deg  = (int*)(ws + o);   o += al((size_t)N * 4);   // reused as cur
    float* dis  = (float*)(ws + o); o += al((size_t)N * 4);
    int*   offs = (int*)(ws + o);   o += al((size_t)N * 4);
    int*   bsum = (int*)(ws + o);   o += al((size_t)nb * 4);
    int*   srcA = (int*)(ws + o);   o += al((size_t)E * 4);
    float* nrm  = (float*)(ws + o); o += al((size_t)E * 4);
    short* w1b  = (short*)(ws + o); o += al((size_t)N_HID * N_HID * 2);
    short* w2b  = (short*)(ws + o); o += al((size_t)N_HID * N_HID * 2);
    short* h    = (short*)(ws + o);                            // N*384 bf16 (76.8 MB)
    int*   cur  = deg;

    // degree (over row) and dis = deg^-0.5
    hipMemsetAsync(deg, 0, (size_t)N * 4, stream);
    k_deg<<<(E + 255) / 256, 256, 0, stream>>>(row, deg, E);
    k_dis<<<(N + 255) / 256, 256, 0, stream>>>(deg, dis, N);

    // CSR by destination
    hipMemsetAsync(offs, 0, (size_t)N * 4, stream);
    k_cnt<<<(E + 255) / 256, 256, 0, stream>>>(col, offs, E);
    k_scan1<<<nb, 256, 0, stream>>>(offs, offs, bsum, N);
    k_scan2<<<1, 64, 0, stream>>>(bsum, nb);
    k_scan3<<<(N + 255) / 256, 256, 0, stream>>>(offs, bsum, N);
    hipMemsetAsync(cur, 0, (size_t)N * 4, stream);
    k_fill<<<(E + 255) / 256, 256, 0, stream>>>(row, col, dis, offs, cur, srcA, nrm, E);

    // bf16 pre-conversion
    const int x4 = (int)((size_t)N * N_HID / 4);
    const int w4 = N_HID * N_HID / 4;
    k_cvt<<<(x4 + 255) / 256, 256, 0, stream>>>(x, xb, x4);
    k_cvt<<<(w4 + 255) / 256, 256, 0, stream>>>(W1, w1b, w4);
    k_cvt<<<(w4 + 255) / 256, 256, 0, stream>>>(W2, w2b, w4);

    dim3 ggrid(N_HID / BN, (N + BM - 1) / BM);   // (3, 782)
    const int gat_blocks = (int)(((size_t)N * 64 + 255) / 256);

    // layer 1: h1 = xb@W1^T + b1 ; a1(bf16) = gather(h1)
    k_gemm<<<ggrid, 256, 0, stream>>>(xb, w1b, b1, h, N);
    k_gather<true><<<gat_blocks, 256, 0, stream>>>(h, srcA, nrm, offs, cur, a1, N);

    // layer 2: h2 = a1@W2^T + b2 ; out(fp32) = gather(h2)
    k_gemm<<<ggrid, 256, 0, stream>>>(a1, w2b, b2, h, N);
    k_gather<false><<<gat_blocks, 256, 0, stream>>>(h, srcA, nrm, offs, cur, out, N);
}

// Round 4
// 491.126 us; speedup vs baseline: 3.0164x; 1.2117x over previous
//
#include <hip/hip_runtime.h>
#include <hip/hip_bf16.h>
#include <cstdint>

#define N_HID 384
#define BM 128
#define BN 128
#define BK 64
#define KTILES 6   // N_HID / BK

typedef __attribute__((ext_vector_type(8))) short bf16x8;
typedef __attribute__((ext_vector_type(4))) float f32x4;

static __device__ __forceinline__ short f2bf(float f) {
    union { __hip_bfloat16 h; short s; } u;
    u.h = __float2bfloat16(f);  // RNE
    return u.s;
}

// async global->LDS, 16B per lane; LDS dest = wave-uniform base + lane*16
static __device__ __forceinline__ void gload_lds16(const void* g, void* l) {
    __builtin_amdgcn_global_load_lds(
        (const __attribute__((address_space(1))) void*)g,
        (__attribute__((address_space(3))) void*)l,
        16, 0, 0);
}

// merged edge histograms: deg over row (for norm), cnt over col (for CSR)
__global__ __launch_bounds__(256) void k_hist(const int* __restrict__ row,
                                              const int* __restrict__ col,
                                              int* __restrict__ deg,
                                              int* __restrict__ cnt, int E) {
    int i = blockIdx.x * 256 + threadIdx.x;
    if (i < E) {
        atomicAdd(&deg[row[i]], 1);
        atomicAdd(&cnt[col[i]], 1);
    }
}

__global__ __launch_bounds__(256) void k_dis(const int* __restrict__ deg,
                                             float* __restrict__ dis, int N) {
    int i = blockIdx.x * 256 + threadIdx.x;
    if (i < N) dis[i] = rsqrtf((float)deg[i]);
}

// fp32 -> bf16 (RNE), n4 = n/4
__global__ __launch_bounds__(256) void k_cvt(const float* __restrict__ in,
                                             short* __restrict__ out, int n4) {
    int i = blockIdx.x * 256 + threadIdx.x;
    if (i < n4) {
        float4 v = reinterpret_cast<const float4*>(in)[i];
        short4 s = make_short4(f2bf(v.x), f2bf(v.y), f2bf(v.z), f2bf(v.w));
        reinterpret_cast<short4*>(out)[i] = s;
    }
}

// ---------- CSR-by-destination build ----------

__global__ __launch_bounds__(256) void k_scan1(const int* __restrict__ cnt,
                                               int* __restrict__ offs,
                                               int* __restrict__ bsum, int N) {
    __shared__ int s[256];
    const int t = threadIdx.x;
    const int base = blockIdx.x * 1024 + t * 4;
    int v[4], tot = 0;
    #pragma unroll
    for (int i = 0; i < 4; i++) { v[i] = (base + i < N) ? cnt[base + i] : 0; tot += v[i]; }
    s[t] = tot;
    __syncthreads();
    #pragma unroll
    for (int off = 1; off < 256; off <<= 1) {
        int x = (t >= off) ? s[t - off] : 0;
        __syncthreads();
        s[t] += x;
        __syncthreads();
    }
    if (t == 255) bsum[blockIdx.x] = s[255];
    int run = s[t] - tot;
    #pragma unroll
    for (int i = 0; i < 4; i++) { if (base + i < N) offs[base + i] = run; run += v[i]; }
}

// parallel block-sum scan (nb <= 256; nb = 98 here). Replaces 1-thread serial loop.
__global__ __launch_bounds__(256) void k_scan2(int* __restrict__ bsum, int nb) {
    __shared__ int s[256];
    const int t = threadIdx.x;
    int v = (t < nb) ? bsum[t] : 0;
    s[t] = v;
    __syncthreads();
    #pragma unroll
    for (int off = 1; off < 256; off <<= 1) {
        int x = (t >= off) ? s[t - off] : 0;
        __syncthreads();
        s[t] += x;
        __syncthreads();
    }
    if (t < nb) bsum[t] = s[t] - v;   // exclusive
}

__global__ __launch_bounds__(256) void k_scan3(int* __restrict__ offs,
                                               const int* __restrict__ bsum, int N) {
    int i = blockIdx.x * 256 + threadIdx.x;
    if (i < N) offs[i] += bsum[i >> 10];
}

// slot fill: packed (src, norm) per CSR slot -> one 8B load in gather
__global__ __launch_bounds__(256) void k_fill(const int* __restrict__ row,
                                              const int* __restrict__ col,
                                              const float* __restrict__ dis,
                                              const int* __restrict__ offs,
                                              int* __restrict__ cur,
                                              int2* __restrict__ srcnrm, int E) {
    int e = blockIdx.x * 256 + threadIdx.x;
    if (e >= E) return;
    int r = row[e], c = col[e];
    int slot = offs[c] + atomicAdd(&cur[c], 1);
    int2 p;
    p.x = r;
    p.y = __float_as_int(dis[r] * dis[c]);
    srcnrm[slot] = p;
}

// ---------- GEMM: out(bf16) = A(bf16) @ W(bf16)^T + bias ----------
// 128x128 tile, BK=64, double-buffered global_load_lds prefetch, XOR-swizzled
// LDS chunks (bank-conflict-free frag reads), LDS-repacked coalesced epilogue,
// XCD-aware bid swizzle (3 n-blocks of one m-tile land on one XCD).
__global__ __launch_bounds__(256) void k_gemm(const short* __restrict__ A,
                                              const short* __restrict__ W,
                                              const float* __restrict__ bias,
                                              short* __restrict__ out, int M, int MT) {
    __shared__ short As[2][BM][BK];   // 2 x 16 KB
    __shared__ short Bs[2][BN][BK];   // 2 x 16 KB
    const int t = threadIdx.x;
    const int bid = blockIdx.x;
    // bid -> (m,n): XCD c = bid%8 processes bids c, c+8, c+16...; give each XCD
    // 3 consecutive blocks sharing one m-tile (A tile L2 reuse).
    const int m_idx = ((bid >> 3) / 3) * 8 + (bid & 7);
    const int n_idx = (bid >> 3) % 3;
    if (m_idx >= MT) return;          // block-uniform exit (before any barrier)
    const int m0 = m_idx * BM, n0 = n_idx * BN;
    const int wave = t >> 6, lane = t & 63;
    const int wm = (wave & 1) * 64, wn = (wave >> 1) * 64;
    const int l16 = lane & 15, quad = lane >> 4;
    const int srow = lane >> 3;                // staging sub-row 0..7
    const int sg8 = ((lane & 7) ^ srow) * 8;   // swizzled global chunk (shorts)
    const int sbase = wave * 8;                // wave's 8-row slab per 32-row group

    f32x4 acc[4][4] = {};

    auto stage = [&](int b, int kt) {
        #pragma unroll
        for (int p = 0; p < 4; p++) {
            int gm = m0 + p * 32 + sbase + srow;
            gm = gm < M ? gm : M - 1;
            gload_lds16(A + (size_t)gm * N_HID + kt + sg8, &As[b][p * 32 + sbase][0]);
        }
        #pragma unroll
        for (int p = 0; p < 4; p++) {
            int gn = n0 + p * 32 + sbase + srow;
            gload_lds16(W + (size_t)gn * N_HID + kt + sg8, &Bs[b][p * 32 + sbase][0]);
        }
    };

    stage(0, 0);
    #pragma unroll
    for (int kt6 = 0; kt6 < KTILES; kt6++) {
        const int b = kt6 & 1;                 // constant after unroll
        __syncthreads();                       // tile kt6 resident (vmcnt0 + barrier)
        if (kt6 + 1 < KTILES) stage(1 - b, (kt6 + 1) * BK);   // prefetch in flight
        #pragma unroll
        for (int kk = 0; kk < 2; kk++) {
            const int gc = kk * 4 + quad;      // global 8-short chunk 0..7
            bf16x8 af[4], bfr[4];
            #pragma unroll
            for (int i = 0; i < 4; i++) {
                int rr = wm + i * 16 + l16;
                af[i] = *reinterpret_cast<const bf16x8*>(&As[b][rr][(gc ^ (l16 & 7)) * 8]);
            }
            #pragma unroll
            for (int j = 0; j < 4; j++) {
                int rr = wn + j * 16 + l16;
                bfr[j] = *reinterpret_cast<const bf16x8*>(&Bs[b][rr][(gc ^ (l16 & 7)) * 8]);
            }
            #pragma unroll
            for (int i = 0; i < 4; i++)
                #pragma unroll
                for (int j = 0; j < 4; j++)
                    acc[i][j] = __builtin_amdgcn_mfma_f32_16x16x32_bf16(af[i], bfr[j], acc[i][j], 0, 0, 0);
        }
    }

    // ---- epilogue: C/D layout (col=l16, row=quad*4+reg) -> LDS repack -> 16B stores
    __syncthreads();                            // all frag reads done; reuse As as scratch
    short* eps = &As[0][0][0] + wave * 4096;    // 8 KB/wave: 64x64 bf16, chunk-swizzled
    #pragma unroll
    for (int j = 0; j < 4; j++) {
        float bv = bias[n0 + wn + j * 16 + l16];
        #pragma unroll
        for (int i = 0; i < 4; i++)
            #pragma unroll
            for (int r = 0; r < 4; r++) {
                int rw = i * 16 + quad * 4 + r;           // row in wave tile
                int colw = j * 16 + l16;                  // col in wave tile
                int chs = ((colw >> 3) + (rw & 7) + (rw >> 3)) & 7;
                eps[rw * 64 + chs * 8 + (colw & 7)] = f2bf(acc[i][j][r] + bv);
            }
    }
    __syncthreads();
    const int r8 = lane >> 3, ch2 = lane & 7;
    #pragma unroll
    for (int pass = 0; pass < 8; pass++) {
        int rw = pass * 8 + r8;
        int chs = (ch2 + r8 + pass) & 7;
        bf16x8 v = *reinterpret_cast<const bf16x8*>(&eps[rw * 64 + chs * 8]);
        int gm = m0 + wm + rw;
        if (gm < M)
            *reinterpret_cast<bf16x8*>(out + (size_t)gm * N_HID + n0 + wn + ch2 * 8) = v;
    }
}

// ---------- gather: one wave per destination node, no atomics ----------
template <bool BF16OUT>
__global__ __launch_bounds__(256) void k_gather(const short* __restrict__ h,
                                                const int2* __restrict__ srcnrm,
                                                const int* __restrict__ offs,
                                                const int* __restrict__ cur,
                                                void* __restrict__ outv, int N) {
    int node = (blockIdx.x * 256 + threadIdx.x) >> 6;
    if (node >= N) return;
    int lane = threadIdx.x & 63;
    int start = offs[node];
    int ecnt  = cur[node];   // in-degree
    float2 acc[3] = {};
    for (int i = 0; i < ecnt; i++) {
        int2 p = srcnrm[start + i];            // wave-uniform -> scalarized 8B load
        int s = p.x;
        float w = __int_as_float(p.y);
        const unsigned int* hr = reinterpret_cast<const unsigned int*>(h + (size_t)s * N_HID);
        #pragma unroll
        for (int k = 0; k < 3; k++) {
            unsigned int pk = hr[lane + 64 * k];
            acc[k].x += w * __uint_as_float(pk << 16);
            acc[k].y += w * __uint_as_float(pk & 0xffff0000u);
        }
    }
    if (BF16OUT) {
        unsigned int* oc = reinterpret_cast<unsigned int*>(outv) + (size_t)node * 192;
        #pragma unroll
        for (int k = 0; k < 3; k++) {
            unsigned int lo = (unsigned int)(unsigned short)f2bf(acc[k].x);
            unsigned int hi = (unsigned int)(unsigned short)f2bf(acc[k].y);
            oc[lane + 64 * k] = lo | (hi << 16);
        }
    } else {
        float2* oc = reinterpret_cast<float2*>(outv) + (size_t)node * 192;
        #pragma unroll
        for (int k = 0; k < 3; k++) oc[lane + 64 * k] = acc[k];
    }
}

extern "C" void kernel_launch(void* const* d_in, const int* in_sizes, int n_in,
                              void* d_out, int out_size, void* d_ws, size_t ws_size,
                              hipStream_t stream) {
    const float* x  = (const float*)d_in[0];
    const int*   ei = (const int*)d_in[1];
    const float* W1 = (const float*)d_in[2];
    const float* b1 = (const float*)d_in[3];
    const float* W2 = (const float*)d_in[4];
    const float* b2 = (const float*)d_in[5];
    float* out = (float*)d_out;

    const int N = in_sizes[0] / N_HID;   // 100000
    const int E = in_sizes[1] / 2;       // 200000
    const int* row = ei;
    const int* col = ei + E;
    const int nb = (N + 1023) / 1024;    // 98 (must be <= 256 for k_scan2)

    // d_out doubles as scratch (disjoint lifetimes; gather-2 fully rewrites it):
    short* xb = (short*)d_out;                          // cvt -> gemm1
    short* a1 = (short*)d_out + (size_t)N * N_HID;      // gather1 -> gemm2

    auto al = [](size_t v) { return (v + 255) & ~(size_t)255; };
    char* ws = (char*)d_ws;
    size_t o = 0;
    int*   deg    = (int*)(ws + o);   o += al((size_t)N * 4);   // reused as cur
    int*   offs   = (int*)(ws + o);   o += al((size_t)N * 4);   // cnt -> offs in place
    float* dis    = (float*)(ws + o); o += al((size_t)N * 4);
    int*   bsum   = (int*)(ws + o);   o += al((size_t)nb * 4);
    int2*  srcnrm = (int2*)(ws + o);  o += al((size_t)E * 8);
    short* w1b    = (short*)(ws + o); o += al((size_t)N_HID * N_HID * 2);
    short* w2b    = (short*)(ws + o); o += al((size_t)N_HID * N_HID * 2);
    short* h      = (short*)(ws + o);                            // N*384 bf16
    int*   cur    = deg;

    // deg (row) + cnt (col) in one edge pass; deg+offs zeroed by one memset
    hipMemsetAsync(deg, 0, al((size_t)N * 4) + (size_t)N * 4, stream);
    k_hist<<<(E + 255) / 256, 256, 0, stream>>>(row, col, deg, offs, E);
    k_dis<<<(N + 255) / 256, 256, 0, stream>>>(deg, dis, N);

    // CSR by destination
    k_scan1<<<nb, 256, 0, stream>>>(offs, offs, bsum, N);
    k_scan2<<<1, 256, 0, stream>>>(bsum, nb);
    k_scan3<<<(N + 255) / 256, 256, 0, stream>>>(offs, bsum, N);
    hipMemsetAsync(cur, 0, (size_t)N * 4, stream);   // deg reuse (k_dis done)
    k_fill<<<(E + 255) / 256, 256, 0, stream>>>(row, col, dis, offs, cur, srcnrm, E);

    // bf16 pre-conversion
    const int x4 = (int)((size_t)N * N_HID / 4);
    const int w4 = N_HID * N_HID / 4;
    k_cvt<<<(x4 + 255) / 256, 256, 0, stream>>>(x, xb, x4);
    k_cvt<<<(w4 + 255) / 256, 256, 0, stream>>>(W1, w1b, w4);
    k_cvt<<<(w4 + 255) / 256, 256, 0, stream>>>(W2, w2b, w4);

    const int MT = (N + BM - 1) / BM;              // 782 m-tiles
    const int gblocks = ((MT + 7) / 8) * 24;       // 98 groups x (8 XCD x 3 n)
    const int gat_blocks = (int)(((size_t)N * 64 + 255) / 256);

    // layer 1: h1 = xb@W1^T + b1 ; a1(bf16) = gather(h1)
    k_gemm<<<gblocks, 256, 0, stream>>>(xb, w1b, b1, h, N, MT);
    k_gather<true><<<gat_blocks, 256, 0, stream>>>(h, srcnrm, offs, cur, a1, N);

    // layer 2: h2 = a1@W2^T + b2 ; out(fp32) = gather(h2)
    k_gemm<<<gblocks, 256, 0, stream>>>(a1, w2b, b2, h, N, MT);
    k_gather<false><<<gat_blocks, 256, 0, stream>>>(h, srcnrm, offs, cur, out, N);
}

// Round 5
// 466.545 us; speedup vs baseline: 3.1753x; 1.0527x over previous
//
#include <hip/hip_runtime.h>
#include <hip/hip_bf16.h>
#include <cstdint>

#define N_HID 384
#define BM 128
#define BN 128
#define BK 64
#define KTILES 6   // N_HID / BK

typedef __attribute__((ext_vector_type(8))) short bf16x8;
typedef __attribute__((ext_vector_type(4))) float f32x4;

static __device__ __forceinline__ short f2bf(float f) {
    union { __hip_bfloat16 h; short s; } u;
    u.h = __float2bfloat16(f);  // RNE
    return u.s;
}

// async global->LDS, 16B per lane; LDS dest = wave-uniform base + lane*16
static __device__ __forceinline__ void gload_lds16(const void* g, void* l) {
    __builtin_amdgcn_global_load_lds(
        (const __attribute__((address_space(1))) void*)g,
        (__attribute__((address_space(3))) void*)l,
        16, 0, 0);
}

// merged edge histograms: deg over row (for norm), cnt over col (for CSR)
__global__ __launch_bounds__(256) void k_hist(const int* __restrict__ row,
                                              const int* __restrict__ col,
                                              int* __restrict__ deg,
                                              int* __restrict__ cnt, int E) {
    int i = blockIdx.x * 256 + threadIdx.x;
    if (i < E) {
        atomicAdd(&deg[row[i]], 1);
        atomicAdd(&cnt[col[i]], 1);
    }
}

// ---------- CSR-by-destination build ----------

__global__ __launch_bounds__(256) void k_scan1(const int* __restrict__ cnt,
                                               int* __restrict__ offs,
                                               int* __restrict__ bsum, int N) {
    __shared__ int s[256];
    const int t = threadIdx.x;
    const int base = blockIdx.x * 1024 + t * 4;
    int v[4], tot = 0;
    #pragma unroll
    for (int i = 0; i < 4; i++) { v[i] = (base + i < N) ? cnt[base + i] : 0; tot += v[i]; }
    s[t] = tot;
    __syncthreads();
    #pragma unroll
    for (int off = 1; off < 256; off <<= 1) {
        int x = (t >= off) ? s[t - off] : 0;
        __syncthreads();
        s[t] += x;
        __syncthreads();
    }
    if (t == 255) bsum[blockIdx.x] = s[255];
    int run = s[t] - tot;
    #pragma unroll
    for (int i = 0; i < 4; i++) { if (base + i < N) offs[base + i] = run; run += v[i]; }
}

__global__ __launch_bounds__(256) void k_scan2(int* __restrict__ bsum, int nb) {
    __shared__ int s[256];
    const int t = threadIdx.x;
    int v = (t < nb) ? bsum[t] : 0;
    s[t] = v;
    __syncthreads();
    #pragma unroll
    for (int off = 1; off < 256; off <<= 1) {
        int x = (t >= off) ? s[t - off] : 0;
        __syncthreads();
        s[t] += x;
        __syncthreads();
    }
    if (t < nb) bsum[t] = s[t] - v;   // exclusive
}

__global__ __launch_bounds__(256) void k_scan3(int* __restrict__ offs,
                                               const int* __restrict__ bsum, int N) {
    int i = blockIdx.x * 256 + threadIdx.x;
    if (i < N) offs[i] += bsum[i >> 10];
}

// slot fill: packed (src, norm) per CSR slot; norm computed from deg directly
__global__ __launch_bounds__(256) void k_fill(const int* __restrict__ row,
                                              const int* __restrict__ col,
                                              const int* __restrict__ deg,
                                              const int* __restrict__ offs,
                                              int* __restrict__ cur,
                                              int2* __restrict__ srcnrm, int E) {
    int e = blockIdx.x * 256 + threadIdx.x;
    if (e >= E) return;
    int r = row[e], c = col[e];
    int slot = offs[c] + atomicAdd(&cur[c], 1);
    int2 p;
    p.x = r;
    p.y = __float_as_int(rsqrtf((float)deg[r]) * rsqrtf((float)deg[c]));
    srcnrm[slot] = p;
}

// ---------- W-prep: w1t = W1^T (bf16), w2b = W2 (bf16), wb1 = W2 @ b1 (fp32)
__global__ __launch_bounds__(256) void k_prep(const float* __restrict__ W1,
                                              const float* __restrict__ W2,
                                              const float* __restrict__ b1,
                                              short* __restrict__ w1t,
                                              short* __restrict__ w2b,
                                              float* __restrict__ wb1) {
    const int bid = blockIdx.x, t = threadIdx.x;
    if (bid < 144) {            // transpose W1 -> bf16, 12x12 tiles of 32x32
        __shared__ short tl[32][33];
        const int tx = bid % 12, ty = bid / 12;
        const int c = t & 31, r8 = t >> 5;      // 32 cols x 8 rows per pass
        #pragma unroll
        for (int rr = 0; rr < 32; rr += 8)
            tl[c][rr + r8] = f2bf(W1[(ty * 32 + rr + r8) * N_HID + tx * 32 + c]);
        __syncthreads();
        #pragma unroll
        for (int rr = 0; rr < 32; rr += 8)
            w1t[(tx * 32 + rr + r8) * N_HID + ty * 32 + c] = tl[rr + r8][c];
    } else if (bid < 288) {     // cvt W2 -> bf16 (float4/short4 per thread)
        int i = (bid - 144) * 256 + t;          // 36864 float4 groups total
        float4 v = reinterpret_cast<const float4*>(W2)[i];
        reinterpret_cast<short4*>(w2b)[i] =
            make_short4(f2bf(v.x), f2bf(v.y), f2bf(v.z), f2bf(v.w));
    } else {                    // wb1[n] = sum_k W2[n][k]*b1[k]; 2 blocks x 192
        int n = (bid - 288) * 192 + t;
        if (t < 192) {
            float s = 0.f;
            for (int k = 0; k < N_HID; k += 4) {
                float4 w = *reinterpret_cast<const float4*>(&W2[n * N_HID + k]);
                float4 b = *reinterpret_cast<const float4*>(&b1[k]);
                s += w.x * b.x + w.y * b.y + w.z * b.z + w.w * b.w;
            }
            wb1[n] = s;
        }
    }
}

// ---------- GEMM: acc[m][n] = sum_k A[m][k]*W[n][k]  (A,W bf16) ----------
// FUSED=false: out bf16 = acc + bias[n]                (tiny W12 = W2*W1)
// FUSED=true : out fp32 = acc + dd[m]*wb1[n] + d[m]*bias[n]   (final output)
template <bool FUSED>
__global__ __launch_bounds__(256) void k_gemm(const short* __restrict__ A,
                                              const short* __restrict__ W,
                                              const float* __restrict__ bias,
                                              const float* __restrict__ wb1,
                                              const float* __restrict__ dvec,
                                              const float* __restrict__ ddvec,
                                              void* __restrict__ outv,
                                              int M, int MT) {
    __shared__ short As[2][BM][BK];
    __shared__ short Bs[2][BN][BK];
    const int t = threadIdx.x;
    const int bid = blockIdx.x;
    // XCD-aware: XCD c=bid%8 gets 3 consecutive blocks sharing one m-tile
    const int m_idx = ((bid >> 3) / 3) * 8 + (bid & 7);
    const int n_idx = (bid >> 3) % 3;
    if (m_idx >= MT) return;
    const int m0 = m_idx * BM, n0 = n_idx * BN;
    const int wave = t >> 6, lane = t & 63;
    const int wm = (wave & 1) * 64, wn = (wave >> 1) * 64;
    const int l16 = lane & 15, quad = lane >> 4;
    const int srow = lane >> 3;
    const int sg8 = ((lane & 7) ^ srow) * 8;   // XOR chunk swizzle
    const int sbase = wave * 8;

    f32x4 acc[4][4] = {};

    auto stage = [&](int b, int kt) {
        #pragma unroll
        for (int p = 0; p < 4; p++) {
            int gm = m0 + p * 32 + sbase + srow;
            gm = gm < M ? gm : M - 1;
            gload_lds16(A + (size_t)gm * N_HID + kt + sg8, &As[b][p * 32 + sbase][0]);
        }
        #pragma unroll
        for (int p = 0; p < 4; p++) {
            int gn = n0 + p * 32 + sbase + srow;
            gload_lds16(W + (size_t)gn * N_HID + kt + sg8, &Bs[b][p * 32 + sbase][0]);
        }
    };

    stage(0, 0);
    #pragma unroll
    for (int kt6 = 0; kt6 < KTILES; kt6++) {
        const int b = kt6 & 1;
        __syncthreads();
        if (kt6 + 1 < KTILES) stage(1 - b, (kt6 + 1) * BK);
        #pragma unroll
        for (int kk = 0; kk < 2; kk++) {
            const int gc = kk * 4 + quad;
            bf16x8 af[4], bfr[4];
            #pragma unroll
            for (int i = 0; i < 4; i++)
                af[i] = *reinterpret_cast<const bf16x8*>(&As[b][wm + i * 16 + l16][(gc ^ (l16 & 7)) * 8]);
            #pragma unroll
            for (int j = 0; j < 4; j++)
                bfr[j] = *reinterpret_cast<const bf16x8*>(&Bs[b][wn + j * 16 + l16][(gc ^ (l16 & 7)) * 8]);
            #pragma unroll
            for (int i = 0; i < 4; i++)
                #pragma unroll
                for (int j = 0; j < 4; j++)
                    acc[i][j] = __builtin_amdgcn_mfma_f32_16x16x32_bf16(af[i], bfr[j], acc[i][j], 0, 0, 0);
        }
    }

    // C/D layout: col = lane&15, row = quad*4 + reg
    if (FUSED) {
        // fp32 direct stores: 16 lanes x 4B = full 64B lines, no RMW
        float* outf = (float*)outv;
        float dv[4][4], ddv[4][4];
        #pragma unroll
        for (int i = 0; i < 4; i++)
            #pragma unroll
            for (int r = 0; r < 4; r++) {
                int gm = m0 + wm + i * 16 + quad * 4 + r;
                int gmc = gm < M ? gm : 0;
                dv[i][r]  = dvec[gmc];
                ddv[i][r] = ddvec[gmc];
            }
        #pragma unroll
        for (int j = 0; j < 4; j++) {
            int gn = n0 + wn + j * 16 + l16;
            float wb1v = wb1[gn];
            float b2v  = bias[gn];
            #pragma unroll
            for (int i = 0; i < 4; i++) {
                int gmb = m0 + wm + i * 16 + quad * 4;
                #pragma unroll
                for (int r = 0; r < 4; r++) {
                    int gm = gmb + r;
                    if (gm < M)
                        outf[(size_t)gm * N_HID + gn] =
                            acc[i][j][r] + ddv[i][r] * wb1v + dv[i][r] * b2v;
                }
            }
        }
    } else {
        // bf16 out via LDS repack -> 16B coalesced stores
        short* outb = (short*)outv;
        __syncthreads();
        short* eps = &As[0][0][0] + wave * 4096;
        #pragma unroll
        for (int j = 0; j < 4; j++) {
            float bv = bias[n0 + wn + j * 16 + l16];
            #pragma unroll
            for (int i = 0; i < 4; i++)
                #pragma unroll
                for (int r = 0; r < 4; r++) {
                    int rw = i * 16 + quad * 4 + r;
                    int colw = j * 16 + l16;
                    int chs = ((colw >> 3) + (rw & 7) + (rw >> 3)) & 7;
                    eps[rw * 64 + chs * 8 + (colw & 7)] = f2bf(acc[i][j][r] + bv);
                }
        }
        __syncthreads();
        const int r8 = lane >> 3, ch2 = lane & 7;
        #pragma unroll
        for (int pass = 0; pass < 8; pass++) {
            int rw = pass * 8 + r8;
            int chs = (ch2 + r8 + pass) & 7;
            bf16x8 v = *reinterpret_cast<const bf16x8*>(&eps[rw * 64 + chs * 8]);
            int gm = m0 + wm + rw;
            if (gm < M)
                *reinterpret_cast<bf16x8*>(outb + (size_t)gm * N_HID + n0 + wn + ch2 * 8) = v;
        }
    }
}

// ---------- gather: one wave per destination node, edge loop unrolled x2 ----
// SECOND=false: in = x (fp32), ds = sum(w)           -> d
// SECOND=true : in = g1 (bf16), ds = sum(w*din[src]) -> dd
template <bool SECOND>
__global__ __launch_bounds__(256) void k_gather(const void* __restrict__ inv,
                                                const int2* __restrict__ srcnrm,
                                                const int* __restrict__ offs,
                                                const int* __restrict__ cur,
                                                const float* __restrict__ din,
                                                unsigned int* __restrict__ outg,
                                                float* __restrict__ dout, int N) {
    int node = (blockIdx.x * 256 + threadIdx.x) >> 6;
    if (node >= N) return;
    int lane = threadIdx.x & 63;
    int start = offs[node];
    int ecnt  = cur[node];   // in-degree
    float2 acc[3] = {};
    float ds = 0.f;
    int i = 0;
    for (; i + 2 <= ecnt; i += 2) {          // pairs: independent load streams
        int2 pa = srcnrm[start + i];
        int2 pb = srcnrm[start + i + 1];
        float wa = __int_as_float(pa.y), wb = __int_as_float(pb.y);
        float2 va[3], vb[3];
        if (SECOND) {
            const unsigned int* ra = (const unsigned int*)inv + (size_t)pa.x * 192;
            const unsigned int* rb = (const unsigned int*)inv + (size_t)pb.x * 192;
            unsigned int ua[3], ub[3];
            #pragma unroll
            for (int k = 0; k < 3; k++) { ua[k] = ra[lane + 64 * k]; ub[k] = rb[lane + 64 * k]; }
            #pragma unroll
            for (int k = 0; k < 3; k++) {
                va[k].x = __uint_as_float(ua[k] << 16);
                va[k].y = __uint_as_float(ua[k] & 0xffff0000u);
                vb[k].x = __uint_as_float(ub[k] << 16);
                vb[k].y = __uint_as_float(ub[k] & 0xffff0000u);
            }
            ds += wa * din[pa.x] + wb * din[pb.x];
        } else {
            const float2* ra = (const float2*)inv + (size_t)pa.x * 192;
            const float2* rb = (const float2*)inv + (size_t)pb.x * 192;
            #pragma unroll
            for (int k = 0; k < 3; k++) { va[k] = ra[lane + 64 * k]; vb[k] = rb[lane + 64 * k]; }
            ds += wa + wb;
        }
        #pragma unroll
        for (int k = 0; k < 3; k++) {
            acc[k].x += wa * va[k].x; acc[k].y += wa * va[k].y;
            acc[k].x += wb * vb[k].x; acc[k].y += wb * vb[k].y;
        }
    }
    if (i < ecnt) {                          // tail edge
        int2 p = srcnrm[start + i];
        float w = __int_as_float(p.y);
        if (SECOND) {
            const unsigned int* r = (const unsigned int*)inv + (size_t)p.x * 192;
            #pragma unroll
            for (int k = 0; k < 3; k++) {
                unsigned int u = r[lane + 64 * k];
                acc[k].x += w * __uint_as_float(u << 16);
                acc[k].y += w * __uint_as_float(u & 0xffff0000u);
            }
            ds += w * din[p.x];
        } else {
            const float2* r = (const float2*)inv + (size_t)p.x * 192;
            #pragma unroll
            for (int k = 0; k < 3; k++) {
                float2 v = r[lane + 64 * k];
                acc[k].x += w * v.x; acc[k].y += w * v.y;
            }
            ds += w;
        }
    }
    #pragma unroll
    for (int k = 0; k < 3; k++) {
        unsigned int lo = (unsigned int)(unsigned short)f2bf(acc[k].x);
        unsigned int hi = (unsigned int)(unsigned short)f2bf(acc[k].y);
        outg[(size_t)node * 192 + lane + 64 * k] = lo | (hi << 16);
    }
    if (lane == 0) dout[node] = ds;
}

extern "C" void kernel_launch(void* const* d_in, const int* in_sizes, int n_in,
                              void* d_out, int out_size, void* d_ws, size_t ws_size,
                              hipStream_t stream) {
    const float* x  = (const float*)d_in[0];
    const int*   ei = (const int*)d_in[1];
    const float* W1 = (const float*)d_in[2];
    const float* b1 = (const float*)d_in[3];
    const float* W2 = (const float*)d_in[4];
    const float* b2 = (const float*)d_in[5];

    const int N = in_sizes[0] / N_HID;   // 100000
    const int E = in_sizes[1] / 2;       // 200000
    const int* row = ei;
    const int* col = ei + E;
    const int nb = (N + 1023) / 1024;    // 98 (<=256 for k_scan2)

    // g1 (bf16, 76.8 MB) lives in d_out's first half; dead before the final
    // GEMM rewrites all of d_out in fp32.
    unsigned int* g1 = (unsigned int*)d_out;

    auto al = [](size_t v) { return (v + 255) & ~(size_t)255; };
    char* ws = (char*)d_ws;
    size_t o = 0;
    int*   deg    = (int*)(ws + o);   o += al((size_t)N * 4);
    int*   offs   = (int*)(ws + o);   o += al((size_t)N * 4);   // cnt -> offs in place
    float* zeros  = (float*)(ws + o); o += al(N_HID * 4);       // tiny-GEMM bias
    int*   cur    = (int*)(ws + o);   o += al((size_t)N * 4);
    // --- everything above zeroed by ONE memset ---
    const size_t zlen = o;
    int*   bsum   = (int*)(ws + o);   o += al((size_t)nb * 4);
    int2*  srcnrm = (int2*)(ws + o);  o += al((size_t)E * 8);
    short* w1t    = (short*)(ws + o); o += al((size_t)N_HID * N_HID * 2);
    short* w2b    = (short*)(ws + o); o += al((size_t)N_HID * N_HID * 2);
    short* w12    = (short*)(ws + o); o += al((size_t)N_HID * N_HID * 2);
    float* wb1    = (float*)(ws + o); o += al(N_HID * 4);
    float* dvec   = (float*)(ws + o); o += al((size_t)N * 4);
    float* ddvec  = (float*)(ws + o); o += al((size_t)N * 4);
    unsigned int* g2 = (unsigned int*)(ws + o);                  // N*384 bf16

    hipMemsetAsync(deg, 0, zlen, stream);

    // CSR build: deg/cnt histograms -> scan -> slot fill (norm from deg)
    k_hist<<<(E + 255) / 256, 256, 0, stream>>>(row, col, deg, offs, E);
    k_scan1<<<nb, 256, 0, stream>>>(offs, offs, bsum, N);
    k_scan2<<<1, 256, 0, stream>>>(bsum, nb);
    k_scan3<<<(N + 255) / 256, 256, 0, stream>>>(offs, bsum, N);
    k_fill<<<(E + 255) / 256, 256, 0, stream>>>(row, col, deg, offs, cur, srcnrm, E);

    // W-prep + tiny GEMM: w12 = W2 @ W1 (bf16), wb1 = W2 @ b1
    k_prep<<<290, 256, 0, stream>>>(W1, W2, b1, w1t, w2b, wb1);
    k_gemm<false><<<24, 256, 0, stream>>>(w2b, w1t, zeros, nullptr, nullptr, nullptr,
                                          w12, N_HID, 3);

    // g1 = A_hat @ x (fp32 in, bf16 out), d = A_hat @ 1
    // g2 = A_hat @ g1,                    dd = A_hat @ d
    const int gat_blocks = (int)(((size_t)N * 64 + 255) / 256);
    k_gather<false><<<gat_blocks, 256, 0, stream>>>(x,  srcnrm, offs, cur, nullptr, g1, dvec, N);
    k_gather<true><<<gat_blocks, 256, 0, stream>>>(g1, srcnrm, offs, cur, dvec, g2, ddvec, N);

    // out = g2 @ w12^T + dd*wb1^T + d*b2^T   (fp32, fully rewrites d_out)
    const int MT = (N + BM - 1) / BM;            // 782
    const int gblocks = ((MT + 7) / 8) * 24;     // 2352
    k_gemm<true><<<gblocks, 256, 0, stream>>>((const short*)g2, w12, b2, wb1, dvec, ddvec,
                                              d_out, N, MT);
}